// Round 3
// baseline (247.363 us; speedup 1.0000x reference)
//
#include <hip/hip_runtime.h>
#include <hip/hip_bf16.h>

#define N_NODES 40000
#define N_EDGES 640000
#define DIM     128

typedef __attribute__((ext_vector_type(8))) short short8;
typedef __attribute__((ext_vector_type(4))) float f32x4;

__device__ inline short f2bf(float f) {
    __hip_bfloat16 h = __float2bfloat16(f);
    return *reinterpret_cast<short*>(&h);
}
__device__ inline float bf2f(short u) {
    union { unsigned int i; float f; } x;
    x.i = ((unsigned int)(unsigned short)u) << 16;
    return x.f;
}

// fragment-order index for element (k,n) of a 128x128 W, matching the
// MFMA B-fragment read: lane l reads slot (kb*8+nt)*64 + l as short8.
__device__ inline int fragidx(int k, int n) {
    int kb = k >> 5, kq = (k >> 3) & 3, j = k & 7;
    int nt = n >> 4, nl = n & 15;
    return (((kb * 8 + nt) * 64 + kq * 16 + nl) * 8 + j);
}

// ---------------------------------------------------------------------------
// prep: WtF = frag(Wt), W1F = frag(W1), WfF = frag(Wt@W0), btf = bt@W0
// grid: 64 blocks x 256 threads, one thread per (k,n) element.
// ---------------------------------------------------------------------------
__global__ __launch_bounds__(256) void prep_kernel(const float* __restrict__ Wt,
                                                   const float* __restrict__ W0,
                                                   const float* __restrict__ W1,
                                                   const float* __restrict__ bt,
                                                   short* __restrict__ WtF,
                                                   short* __restrict__ WfF,
                                                   short* __restrict__ W1F,
                                                   float* __restrict__ btf) {
    int gid = blockIdx.x * 256 + threadIdx.x;   // 0..16383
    int k = gid >> 7, n = gid & 127;
    float wf = 0.f;
    for (int kk = 0; kk < 128; ++kk)
        wf += Wt[k * 128 + kk] * W0[kk * 128 + n];
    int fi = fragidx(k, n);
    WtF[fi] = f2bf(Wt[k * 128 + n]);
    W1F[fi] = f2bf(W1[k * 128 + n]);
    WfF[fi] = f2bf(wf);
    if (gid < 128) {
        float s = 0.f;
        for (int kk = 0; kk < 128; ++kk) s += bt[kk] * W0[kk * 128 + n];
        btf[n] = s;
    }
}

// ---------------------------------------------------------------------------
// dual GEMM over x: H = x@WtF + bt (f32), Z = x@WfF + btf (bf16)
// 64 rows/block, 4 waves, no LDS; W-frags read straight from global (L1/L2).
// ---------------------------------------------------------------------------
__global__ __launch_bounds__(256) void dual_gemm(const float* __restrict__ A,
                                                 const short* __restrict__ WtF,
                                                 const short* __restrict__ WfF,
                                                 const float* __restrict__ bt,
                                                 const float* __restrict__ btf,
                                                 float* __restrict__ H,
                                                 __hip_bfloat16* __restrict__ Z) {
    const int t    = threadIdx.x;
    const int wave = t >> 6;
    const int l    = t & 63;
    const int nl   = l & 15;
    const int quad = l >> 4;
    const int wRow = blockIdx.x * 64 + wave * 16;

    f32x4 accH[8], accZ[8];
#pragma unroll
    for (int nt = 0; nt < 8; ++nt) {
        accH[nt] = (f32x4){0.f, 0.f, 0.f, 0.f};
        accZ[nt] = (f32x4){0.f, 0.f, 0.f, 0.f};
    }

#pragma unroll
    for (int kb = 0; kb < 4; ++kb) {
        const float* ap = A + (size_t)(wRow + nl) * 128 + kb * 32 + quad * 8;
        float4 f0 = *(const float4*)ap;
        float4 f1 = *(const float4*)(ap + 4);
        short8 afrag;
        afrag[0] = f2bf(f0.x); afrag[1] = f2bf(f0.y);
        afrag[2] = f2bf(f0.z); afrag[3] = f2bf(f0.w);
        afrag[4] = f2bf(f1.x); afrag[5] = f2bf(f1.y);
        afrag[6] = f2bf(f1.z); afrag[7] = f2bf(f1.w);
#pragma unroll
        for (int nt = 0; nt < 8; ++nt) {
            int off = ((kb * 8 + nt) * 64 + l) * 8;
            short8 bt_frag = *(const short8*)&WtF[off];
            short8 bf_frag = *(const short8*)&WfF[off];
            accH[nt] = __builtin_amdgcn_mfma_f32_16x16x32_bf16(afrag, bt_frag, accH[nt], 0, 0, 0);
            accZ[nt] = __builtin_amdgcn_mfma_f32_16x16x32_bf16(afrag, bf_frag, accZ[nt], 0, 0, 0);
        }
    }

#pragma unroll
    for (int nt = 0; nt < 8; ++nt) {
        int col = nt * 16 + nl;
        float bH = bt[col];
        float bZ = btf[col];
#pragma unroll
        for (int r = 0; r < 4; ++r) {
            int row = wRow + quad * 4 + r;
            H[(size_t)row * 128 + col] = accH[nt][r] + bH;
            *(short*)&Z[(size_t)row * 128 + col] = f2bf(accZ[nt][r] + bZ);
        }
    }
}

// ---------------------------------------------------------------------------
// bf16-A GEMM: Z = Hb@W1F (bf16 out, no bias), same structure.
// ---------------------------------------------------------------------------
__global__ __launch_bounds__(256) void gemm_bf16(const __hip_bfloat16* __restrict__ Hb,
                                                 const short* __restrict__ WF,
                                                 __hip_bfloat16* __restrict__ Z) {
    const int t    = threadIdx.x;
    const int wave = t >> 6;
    const int l    = t & 63;
    const int nl   = l & 15;
    const int quad = l >> 4;
    const int wRow = blockIdx.x * 64 + wave * 16;

    f32x4 acc[8];
#pragma unroll
    for (int nt = 0; nt < 8; ++nt) acc[nt] = (f32x4){0.f, 0.f, 0.f, 0.f};

#pragma unroll
    for (int kb = 0; kb < 4; ++kb) {
        short8 afrag = *(const short8*)((const short*)Hb + (size_t)(wRow + nl) * 128 + kb * 32 + quad * 8);
#pragma unroll
        for (int nt = 0; nt < 8; ++nt) {
            short8 bfrag = *(const short8*)&WF[((kb * 8 + nt) * 64 + l) * 8];
            acc[nt] = __builtin_amdgcn_mfma_f32_16x16x32_bf16(afrag, bfrag, acc[nt], 0, 0, 0);
        }
    }

#pragma unroll
    for (int nt = 0; nt < 8; ++nt) {
        int col = nt * 16 + nl;
#pragma unroll
        for (int r = 0; r < 4; ++r) {
            int row = wRow + quad * 4 + r;
            *(short*)&Z[(size_t)row * 128 + col] = f2bf(acc[nt][r]);
        }
    }
}

// ---------------------------------------------------------------------------
// CSR build
// ---------------------------------------------------------------------------
__global__ void hist_kernel(const int* __restrict__ rows, int* __restrict__ counts) {
    int e = blockIdx.x * 256 + threadIdx.x;
    if (e < N_EDGES) atomicAdd(&counts[rows[e]], 1);
}

__global__ __launch_bounds__(256) void scan_local(const int* __restrict__ counts,
                                                  int* __restrict__ excl,
                                                  int* __restrict__ blkTot) {
    __shared__ int sh[256];
    const int t = threadIdx.x;
    int i = blockIdx.x * 256 + t;
    int c = (i < N_NODES) ? counts[i] : 0;
    int val = c;
    sh[t] = val;
    __syncthreads();
    for (int off = 1; off < 256; off <<= 1) {
        int a = (t >= off) ? sh[t - off] : 0;
        __syncthreads();
        val += a;
        sh[t] = val;
        __syncthreads();
    }
    if (i < N_NODES) excl[i] = val - c;
    if (t == 255) blkTot[blockIdx.x] = val;
}

__global__ __launch_bounds__(256) void scan_blk(const int* __restrict__ blkTot,
                                                int* __restrict__ blkOff,
                                                int nblk) {
    __shared__ int sh[256];
    const int t = threadIdx.x;
    int c = (t < nblk) ? blkTot[t] : 0;
    int val = c;
    sh[t] = val;
    __syncthreads();
    for (int off = 1; off < 256; off <<= 1) {
        int a = (t >= off) ? sh[t - off] : 0;
        __syncthreads();
        val += a;
        sh[t] = val;
        __syncthreads();
    }
    if (t < nblk) blkOff[t] = val - c;
}

__global__ __launch_bounds__(256) void scan_final(const int* __restrict__ excl,
                                                  const int* __restrict__ blkOff,
                                                  int* __restrict__ cursor,
                                                  int* __restrict__ row_ptr) {
    int i = blockIdx.x * 256 + threadIdx.x;
    if (i < N_NODES) {
        int v = excl[i] + blkOff[blockIdx.x];
        cursor[i]  = v;
        row_ptr[i] = v;
    }
    if (i == 0) row_ptr[N_NODES] = N_EDGES;
}

__global__ void scatter_kernel(const int* __restrict__ rows,
                               const int* __restrict__ cols,
                               int* __restrict__ cursor,
                               int* __restrict__ adj) {
    int e = blockIdx.x * 256 + threadIdx.x;
    if (e < N_EDGES) {
        int r   = rows[e];
        int pos = atomicAdd(&cursor[r], 1);
        adj[pos] = cols[e];
    }
}

// ---------------------------------------------------------------------------
// Aggregation: one wave per node, 4 edges/group, 2 groups in flight.
// h[node] += relu(sum_edges z[adj] + bias); optionally write Hb = bf16(h).
// ---------------------------------------------------------------------------
template <int WRITE_HB>
__global__ __launch_bounds__(256) void agg_kernel(const __hip_bfloat16* __restrict__ z,
                                                  const int* __restrict__ row_ptr,
                                                  const int* __restrict__ adj,
                                                  const float* __restrict__ bias,
                                                  float* __restrict__ h,
                                                  __hip_bfloat16* __restrict__ Hb) {
    const int wave = threadIdx.x >> 6;
    const int l    = threadIdx.x & 63;
    const int quad = l >> 4;
    const int sl   = l & 15;
    const int node = blockIdx.x * 4 + wave;
    if (node >= N_NODES) return;

    const int s = row_ptr[node];
    const int e = row_ptr[node + 1];

    float acc[8];
#pragma unroll
    for (int j = 0; j < 8; ++j) acc[j] = 0.f;

    int it = s + quad;
    for (; it + 4 < e; it += 8) {
        int c0 = adj[it];
        int c1 = adj[it + 4];
        short8 v0 = *(const short8*)&z[(size_t)c0 * DIM + sl * 8];
        short8 v1 = *(const short8*)&z[(size_t)c1 * DIM + sl * 8];
#pragma unroll
        for (int j = 0; j < 8; ++j) acc[j] += bf2f(v0[j]);
#pragma unroll
        for (int j = 0; j < 8; ++j) acc[j] += bf2f(v1[j]);
    }
    if (it < e) {
        int c = adj[it];
        short8 v = *(const short8*)&z[(size_t)c * DIM + sl * 8];
#pragma unroll
        for (int j = 0; j < 8; ++j) acc[j] += bf2f(v[j]);
    }

#pragma unroll
    for (int j = 0; j < 8; ++j) acc[j] += __shfl_xor(acc[j], 16, 64);
#pragma unroll
    for (int j = 0; j < 8; ++j) acc[j] += __shfl_xor(acc[j], 32, 64);

    if (quad == 0) {
        float* hp = h + (size_t)node * DIM + sl * 8;
        float4 h0 = *(float4*)hp;
        float4 h1 = *(float4*)(hp + 4);
        float4 b0 = *(const float4*)&bias[sl * 8];
        float4 b1 = *(const float4*)&bias[sl * 8 + 4];
        float r0 = acc[0] + b0.x, r1 = acc[1] + b0.y, r2 = acc[2] + b0.z, r3 = acc[3] + b0.w;
        float r4 = acc[4] + b1.x, r5 = acc[5] + b1.y, r6 = acc[6] + b1.z, r7 = acc[7] + b1.w;
        h0.x += r0 > 0.f ? r0 : 0.f;  h0.y += r1 > 0.f ? r1 : 0.f;
        h0.z += r2 > 0.f ? r2 : 0.f;  h0.w += r3 > 0.f ? r3 : 0.f;
        h1.x += r4 > 0.f ? r4 : 0.f;  h1.y += r5 > 0.f ? r5 : 0.f;
        h1.z += r6 > 0.f ? r6 : 0.f;  h1.w += r7 > 0.f ? r7 : 0.f;
        *(float4*)hp       = h0;
        *(float4*)(hp + 4) = h1;
        if (WRITE_HB) {
            short8 hb;
            hb[0] = f2bf(h0.x); hb[1] = f2bf(h0.y); hb[2] = f2bf(h0.z); hb[3] = f2bf(h0.w);
            hb[4] = f2bf(h1.x); hb[5] = f2bf(h1.y); hb[6] = f2bf(h1.z); hb[7] = f2bf(h1.w);
            *(short8*)((short*)Hb + (size_t)node * DIM + sl * 8) = hb;
        }
    }
}

// ---------------------------------------------------------------------------
extern "C" void kernel_launch(void* const* d_in, const int* in_sizes, int n_in,
                              void* d_out, int out_size, void* d_ws, size_t ws_size,
                              hipStream_t stream) {
    const float* x   = (const float*)d_in[0];
    const int*   ei  = (const int*)d_in[1];
    const float* W_t = (const float*)d_in[2];
    const float* b_t = (const float*)d_in[3];
    const float* W0  = (const float*)d_in[4];
    const float* b0  = (const float*)d_in[5];
    const float* W1  = (const float*)d_in[6];
    const float* b1  = (const float*)d_in[7];

    const int* rows = ei;
    const int* cols = ei + N_EDGES;

    float* H = (float*)d_out;

    // workspace layout
    char* w = (char*)d_ws;
    __hip_bfloat16* Z  = (__hip_bfloat16*)w;  w += (size_t)N_NODES * DIM * 2;
    __hip_bfloat16* Hb = (__hip_bfloat16*)w;  w += (size_t)N_NODES * DIM * 2;
    short* WtF = (short*)w;  w += 128 * 128 * 2;
    short* WfF = (short*)w;  w += 128 * 128 * 2;
    short* W1F = (short*)w;  w += 128 * 128 * 2;
    float* btf = (float*)w;  w += 128 * 4;
    int* row_ptr = (int*)w;  w += (N_NODES + 1) * 4;
    int* cursor  = (int*)w;  w += N_NODES * 4;
    int* counts  = (int*)w;  w += N_NODES * 4;
    int* excl    = (int*)w;  w += N_NODES * 4;
    int* adj     = (int*)w;  w += (size_t)N_EDGES * 4;
    int* blkTot  = (int*)w;  w += 256 * 4;
    int* blkOff  = (int*)w;

    const int eb = (N_EDGES + 255) / 256;   // 2500
    const int nb = (N_NODES + 255) / 256;   // 157
    const int gemmBlocks = N_NODES / 64;    // 625
    const int aggBlocks  = (N_NODES + 3) / 4;

    // CSR build
    hipMemsetAsync(counts, 0, N_NODES * sizeof(int), stream);
    hist_kernel<<<eb, 256, 0, stream>>>(rows, counts);
    scan_local<<<nb, 256, 0, stream>>>(counts, excl, blkTot);
    scan_blk<<<1, 256, 0, stream>>>(blkTot, blkOff, nb);
    scan_final<<<nb, 256, 0, stream>>>(excl, blkOff, cursor, row_ptr);
    scatter_kernel<<<eb, 256, 0, stream>>>(rows, cols, cursor, adj);

    // weight prep (frag-order bf16 + fused Wt@W0)
    prep_kernel<<<64, 256, 0, stream>>>(W_t, W0, W1, b_t, WtF, WfF, W1F, btf);

    // H = x@Wt + bt ; Z0 = x@(Wt@W0) + bt@W0   (one pass over x)
    dual_gemm<<<gemmBlocks, 256, 0, stream>>>(x, WtF, WfF, b_t, btf, H, Z);

    // layer 0 agg: H += relu(agg(Z0) + b0), emit Hb = bf16(H)
    agg_kernel<1><<<aggBlocks, 256, 0, stream>>>(Z, row_ptr, adj, b0, H, Hb);

    // layer 1: Z1 = Hb@W1 ; H += relu(agg(Z1) + b1)
    gemm_bf16<<<gemmBlocks, 256, 0, stream>>>(Hb, W1F, Z);
    agg_kernel<0><<<aggBlocks, 256, 0, stream>>>(Z, row_ptr, adj, b1, H, nullptr);
}

// Round 4
// 235.385 us; speedup vs baseline: 1.0509x; 1.0509x over previous
//
#include <hip/hip_runtime.h>
#include <hip/hip_bf16.h>

#define N_NODES 40000
#define N_EDGES 640000
#define DIM     128
#define EB      2500   // edge blocks (256 threads)
#define NB      157    // node blocks (256 threads)

typedef __attribute__((ext_vector_type(8))) short short8;
typedef __attribute__((ext_vector_type(4))) float f32x4;

__device__ inline short f2bf(float f) {
    __hip_bfloat16 h = __float2bfloat16(f);
    return *reinterpret_cast<short*>(&h);
}
__device__ inline float bf2f(short u) {
    union { unsigned int i; float f; } x;
    x.i = ((unsigned int)(unsigned short)u) << 16;
    return x.f;
}

// fragment-order index for element (k,n) of a 128x128 W, matching the
// MFMA B-fragment read: lane l reads slot (kb*8+nt)*64 + l as short8.
__device__ inline int fragidx(int k, int n) {
    int kb = k >> 5, kq = (k >> 3) & 3, j = k & 7;
    int nt = n >> 4, nl = n & 15;
    return (((kb * 8 + nt) * 64 + kq * 16 + nl) * 8 + j);
}

// ---------------------------------------------------------------------------
// hist + weight prep fused (prep is independent work tacked on as 64 blocks)
// ---------------------------------------------------------------------------
__global__ __launch_bounds__(256) void hist_prep(const int* __restrict__ rows,
                                                 int* __restrict__ counts,
                                                 const float* __restrict__ Wt,
                                                 const float* __restrict__ W0,
                                                 const float* __restrict__ W1,
                                                 const float* __restrict__ bt,
                                                 short* __restrict__ WtF,
                                                 short* __restrict__ WfF,
                                                 short* __restrict__ W1F,
                                                 float* __restrict__ btf) {
    int b = blockIdx.x;
    if (b < EB) {
        int e = b * 256 + threadIdx.x;
        if (e < N_EDGES) atomicAdd(&counts[rows[e]], 1);
    } else {
        int gid = (b - EB) * 256 + threadIdx.x;     // 0..16383
        int k = gid >> 7, n = gid & 127;
        float wf = 0.f;
        for (int kk = 0; kk < 128; ++kk)
            wf += Wt[k * 128 + kk] * W0[kk * 128 + n];
        int fi = fragidx(k, n);
        WtF[fi] = f2bf(Wt[k * 128 + n]);
        W1F[fi] = f2bf(W1[k * 128 + n]);
        WfF[fi] = f2bf(wf);
        if (gid < 128) {
            float s = 0.f;
            for (int kk = 0; kk < 128; ++kk) s += bt[kk] * W0[kk * 128 + n];
            btf[n] = s;
        }
    }
}

// ---------------------------------------------------------------------------
// scan pass 1: per-block exclusive scan of counts + block totals
// ---------------------------------------------------------------------------
__global__ __launch_bounds__(256) void scan_local(const int* __restrict__ counts,
                                                  int* __restrict__ excl,
                                                  int* __restrict__ blkTot) {
    __shared__ int sh[256];
    const int t = threadIdx.x;
    int i = blockIdx.x * 256 + t;
    int c = (i < N_NODES) ? counts[i] : 0;
    int val = c;
    sh[t] = val;
    __syncthreads();
    for (int off = 1; off < 256; off <<= 1) {
        int a = (t >= off) ? sh[t - off] : 0;
        __syncthreads();
        val += a;
        sh[t] = val;
        __syncthreads();
    }
    if (i < N_NODES) excl[i] = val - c;
    if (t == 255) blkTot[blockIdx.x] = val;
}

// ---------------------------------------------------------------------------
// scan pass 2: every block redundantly scans the 157 block totals in LDS,
// picks its own offset, finalizes cursor/row_ptr. (one dispatch saved)
// ---------------------------------------------------------------------------
__global__ __launch_bounds__(256) void scan_final(const int* __restrict__ excl,
                                                  const int* __restrict__ blkTot,
                                                  int* __restrict__ cursor,
                                                  int* __restrict__ row_ptr) {
    __shared__ int sh[256];
    const int t = threadIdx.x;
    int v = (t < NB) ? blkTot[t] : 0;
    int val = v;
    sh[t] = val;
    __syncthreads();
    for (int off = 1; off < 256; off <<= 1) {
        int a = (t >= off) ? sh[t - off] : 0;
        __syncthreads();
        val += a;
        sh[t] = val;
        __syncthreads();
    }
    int blkOff = (blockIdx.x == 0) ? 0 : sh[blockIdx.x - 1];
    int i = blockIdx.x * 256 + t;
    if (i < N_NODES) {
        int u = excl[i] + blkOff;
        cursor[i]  = u;
        row_ptr[i] = u;
    }
    if (i == 0) row_ptr[N_NODES] = N_EDGES;
}

__global__ void scatter_kernel(const int* __restrict__ rows,
                               const int* __restrict__ cols,
                               int* __restrict__ cursor,
                               int* __restrict__ adj) {
    int e = blockIdx.x * 256 + threadIdx.x;
    if (e < N_EDGES) {
        int r   = rows[e];
        int pos = atomicAdd(&cursor[r], 1);
        adj[pos] = cols[e];
    }
}

// ---------------------------------------------------------------------------
// dual GEMM over x: Hb = bf16(x@Wt + bt), Z = bf16(x@(Wt@W0) + bt@W0)
// 64 rows/block, 4 waves, W-frags straight from global (L1/L2-resident).
// ---------------------------------------------------------------------------
__global__ __launch_bounds__(256) void dual_gemm(const float* __restrict__ A,
                                                 const short* __restrict__ WtF,
                                                 const short* __restrict__ WfF,
                                                 const float* __restrict__ bt,
                                                 const float* __restrict__ btf,
                                                 __hip_bfloat16* __restrict__ Hb,
                                                 __hip_bfloat16* __restrict__ Z) {
    const int t    = threadIdx.x;
    const int wave = t >> 6;
    const int l    = t & 63;
    const int nl   = l & 15;
    const int quad = l >> 4;
    const int wRow = blockIdx.x * 64 + wave * 16;

    f32x4 accH[8], accZ[8];
#pragma unroll
    for (int nt = 0; nt < 8; ++nt) {
        accH[nt] = (f32x4){0.f, 0.f, 0.f, 0.f};
        accZ[nt] = (f32x4){0.f, 0.f, 0.f, 0.f};
    }

#pragma unroll
    for (int kb = 0; kb < 4; ++kb) {
        const float* ap = A + (size_t)(wRow + nl) * 128 + kb * 32 + quad * 8;
        float4 f0 = *(const float4*)ap;
        float4 f1 = *(const float4*)(ap + 4);
        short8 afrag;
        afrag[0] = f2bf(f0.x); afrag[1] = f2bf(f0.y);
        afrag[2] = f2bf(f0.z); afrag[3] = f2bf(f0.w);
        afrag[4] = f2bf(f1.x); afrag[5] = f2bf(f1.y);
        afrag[6] = f2bf(f1.z); afrag[7] = f2bf(f1.w);
#pragma unroll
        for (int nt = 0; nt < 8; ++nt) {
            int off = ((kb * 8 + nt) * 64 + l) * 8;
            short8 bt_frag = *(const short8*)&WtF[off];
            short8 bf_frag = *(const short8*)&WfF[off];
            accH[nt] = __builtin_amdgcn_mfma_f32_16x16x32_bf16(afrag, bt_frag, accH[nt], 0, 0, 0);
            accZ[nt] = __builtin_amdgcn_mfma_f32_16x16x32_bf16(afrag, bf_frag, accZ[nt], 0, 0, 0);
        }
    }

#pragma unroll
    for (int nt = 0; nt < 8; ++nt) {
        int col = nt * 16 + nl;
        float bH = bt[col];
        float bZ = btf[col];
#pragma unroll
        for (int r = 0; r < 4; ++r) {
            int row = wRow + quad * 4 + r;
            *(short*)&Hb[(size_t)row * 128 + col] = f2bf(accH[nt][r] + bH);
            *(short*)&Z[(size_t)row * 128 + col]  = f2bf(accZ[nt][r] + bZ);
        }
    }
}

// ---------------------------------------------------------------------------
// bf16-A GEMM: Z = Hb@W1F (bf16 out, no bias)
// ---------------------------------------------------------------------------
__global__ __launch_bounds__(256) void gemm_bf16(const __hip_bfloat16* __restrict__ Hb,
                                                 const short* __restrict__ WF,
                                                 __hip_bfloat16* __restrict__ Z) {
    const int t    = threadIdx.x;
    const int wave = t >> 6;
    const int l    = t & 63;
    const int nl   = l & 15;
    const int quad = l >> 4;
    const int wRow = blockIdx.x * 64 + wave * 16;

    f32x4 acc[8];
#pragma unroll
    for (int nt = 0; nt < 8; ++nt) acc[nt] = (f32x4){0.f, 0.f, 0.f, 0.f};

#pragma unroll
    for (int kb = 0; kb < 4; ++kb) {
        short8 afrag = *(const short8*)((const short*)Hb + (size_t)(wRow + nl) * 128 + kb * 32 + quad * 8);
#pragma unroll
        for (int nt = 0; nt < 8; ++nt) {
            short8 bfrag = *(const short8*)&WF[((kb * 8 + nt) * 64 + l) * 8];
            acc[nt] = __builtin_amdgcn_mfma_f32_16x16x32_bf16(afrag, bfrag, acc[nt], 0, 0, 0);
        }
    }

#pragma unroll
    for (int nt = 0; nt < 8; ++nt) {
        int col = nt * 16 + nl;
#pragma unroll
        for (int r = 0; r < 4; ++r) {
            int row = wRow + quad * 4 + r;
            *(short*)&Z[(size_t)row * 128 + col] = f2bf(acc[nt][r]);
        }
    }
}

// ---------------------------------------------------------------------------
// Aggregation: one wave per node, 4 edges/group, up to 4 groups in flight.
// FINAL=0: Hb[node] = bf16(Hb[node] + relu(agg + bias))
// FINAL=1: Hout[node] = f32(Hb[node]) + relu(agg + bias)
// ---------------------------------------------------------------------------
template <int FINAL>
__global__ __launch_bounds__(256) void agg_kernel(const __hip_bfloat16* __restrict__ z,
                                                  const int* __restrict__ row_ptr,
                                                  const int* __restrict__ adj,
                                                  const float* __restrict__ bias,
                                                  __hip_bfloat16* __restrict__ Hb,
                                                  float* __restrict__ Hout) {
    const int wave = threadIdx.x >> 6;
    const int l    = threadIdx.x & 63;
    const int quad = l >> 4;
    const int sl   = l & 15;
    const int node = blockIdx.x * 4 + wave;
    if (node >= N_NODES) return;

    const int s = row_ptr[node];
    const int e = row_ptr[node + 1];

    float acc[8];
#pragma unroll
    for (int j = 0; j < 8; ++j) acc[j] = 0.f;

    int it = s + quad;
    for (; it + 12 < e; it += 16) {
        int c0 = adj[it];
        int c1 = adj[it + 4];
        int c2 = adj[it + 8];
        int c3 = adj[it + 12];
        short8 v0 = *(const short8*)&z[(size_t)c0 * DIM + sl * 8];
        short8 v1 = *(const short8*)&z[(size_t)c1 * DIM + sl * 8];
        short8 v2 = *(const short8*)&z[(size_t)c2 * DIM + sl * 8];
        short8 v3 = *(const short8*)&z[(size_t)c3 * DIM + sl * 8];
#pragma unroll
        for (int j = 0; j < 8; ++j)
            acc[j] += (bf2f(v0[j]) + bf2f(v1[j])) + (bf2f(v2[j]) + bf2f(v3[j]));
    }
    for (; it + 4 < e; it += 8) {
        int c0 = adj[it];
        int c1 = adj[it + 4];
        short8 v0 = *(const short8*)&z[(size_t)c0 * DIM + sl * 8];
        short8 v1 = *(const short8*)&z[(size_t)c1 * DIM + sl * 8];
#pragma unroll
        for (int j = 0; j < 8; ++j) acc[j] += bf2f(v0[j]) + bf2f(v1[j]);
    }
    if (it < e) {
        int c = adj[it];
        short8 v = *(const short8*)&z[(size_t)c * DIM + sl * 8];
#pragma unroll
        for (int j = 0; j < 8; ++j) acc[j] += bf2f(v[j]);
    }

#pragma unroll
    for (int j = 0; j < 8; ++j) acc[j] += __shfl_xor(acc[j], 16, 64);
#pragma unroll
    for (int j = 0; j < 8; ++j) acc[j] += __shfl_xor(acc[j], 32, 64);

    if (quad == 0) {
        short8 hrow = *(const short8*)((const short*)Hb + (size_t)node * DIM + sl * 8);
        float4 b0 = *(const float4*)&bias[sl * 8];
        float4 b1 = *(const float4*)&bias[sl * 8 + 4];
        float r[8];
        r[0] = acc[0] + b0.x; r[1] = acc[1] + b0.y; r[2] = acc[2] + b0.z; r[3] = acc[3] + b0.w;
        r[4] = acc[4] + b1.x; r[5] = acc[5] + b1.y; r[6] = acc[6] + b1.z; r[7] = acc[7] + b1.w;
#pragma unroll
        for (int j = 0; j < 8; ++j) {
            float rr = r[j] > 0.f ? r[j] : 0.f;
            r[j] = bf2f(hrow[j]) + rr;
        }
        if (FINAL) {
            float* hp = Hout + (size_t)node * DIM + sl * 8;
            *(float4*)hp       = make_float4(r[0], r[1], r[2], r[3]);
            *(float4*)(hp + 4) = make_float4(r[4], r[5], r[6], r[7]);
        } else {
            short8 o;
#pragma unroll
            for (int j = 0; j < 8; ++j) o[j] = f2bf(r[j]);
            *(short8*)((short*)Hb + (size_t)node * DIM + sl * 8) = o;
        }
    }
}

// ---------------------------------------------------------------------------
extern "C" void kernel_launch(void* const* d_in, const int* in_sizes, int n_in,
                              void* d_out, int out_size, void* d_ws, size_t ws_size,
                              hipStream_t stream) {
    const float* x   = (const float*)d_in[0];
    const int*   ei  = (const int*)d_in[1];
    const float* W_t = (const float*)d_in[2];
    const float* b_t = (const float*)d_in[3];
    const float* W0  = (const float*)d_in[4];
    const float* b0  = (const float*)d_in[5];
    const float* W1  = (const float*)d_in[6];
    const float* b1  = (const float*)d_in[7];

    const int* rows = ei;
    const int* cols = ei + N_EDGES;

    float* H = (float*)d_out;

    // workspace layout
    char* w = (char*)d_ws;
    __hip_bfloat16* Z  = (__hip_bfloat16*)w;  w += (size_t)N_NODES * DIM * 2;
    __hip_bfloat16* Hb = (__hip_bfloat16*)w;  w += (size_t)N_NODES * DIM * 2;
    short* WtF = (short*)w;  w += 128 * 128 * 2;
    short* WfF = (short*)w;  w += 128 * 128 * 2;
    short* W1F = (short*)w;  w += 128 * 128 * 2;
    float* btf = (float*)w;  w += 128 * 4;
    int* row_ptr = (int*)w;  w += (N_NODES + 1) * 4;
    int* cursor  = (int*)w;  w += N_NODES * 4;
    int* counts  = (int*)w;  w += N_NODES * 4;
    int* excl    = (int*)w;  w += N_NODES * 4;
    int* adj     = (int*)w;  w += (size_t)N_EDGES * 4;
    int* blkTot  = (int*)w;

    const int gemmBlocks = N_NODES / 64;    // 625
    const int aggBlocks  = (N_NODES + 3) / 4;

    // CSR build + weight prep (fused into hist dispatch)
    hipMemsetAsync(counts, 0, N_NODES * sizeof(int), stream);
    hist_prep<<<EB + 64, 256, 0, stream>>>(rows, counts, W_t, W0, W1, b_t,
                                           WtF, WfF, W1F, btf);
    scan_local<<<NB, 256, 0, stream>>>(counts, excl, blkTot);
    scan_final<<<NB, 256, 0, stream>>>(excl, blkTot, cursor, row_ptr);
    scatter_kernel<<<EB, 256, 0, stream>>>(rows, cols, cursor, adj);

    // Hb = bf16(x@Wt + bt) ; Z0 = bf16(x@(Wt@W0) + bt@W0)  (one pass over x)
    dual_gemm<<<gemmBlocks, 256, 0, stream>>>(x, WtF, WfF, b_t, btf, Hb, Z);

    // layer 0: Hb += relu(agg(Z0) + b0)   (bf16 in-place)
    agg_kernel<0><<<aggBlocks, 256, 0, stream>>>(Z, row_ptr, adj, b0, Hb, nullptr);

    // layer 1: Z1 = Hb@W1 ; H = f32(Hb) + relu(agg(Z1) + b1)
    gemm_bf16<<<gemmBlocks, 256, 0, stream>>>(Hb, W1F, Z);
    agg_kernel<1><<<aggBlocks, 256, 0, stream>>>(Z, row_ptr, adj, b1, Hb, H);
}

// Round 5
// 218.944 us; speedup vs baseline: 1.1298x; 1.0751x over previous
//
#include <hip/hip_runtime.h>
#include <hip/hip_bf16.h>

#define N_NODES 40000
#define N_EDGES 640000
#define DIM     128
#define NB      157    // node blocks (256 threads)
#define GEMMB   625    // gemm blocks (64 rows each)
#define HEB     1250   // hist/scatter blocks (2 edges/thread)

typedef __attribute__((ext_vector_type(8))) short short8;
typedef __attribute__((ext_vector_type(4))) float f32x4;

__device__ inline short f2bf(float f) {
    __hip_bfloat16 h = __float2bfloat16(f);
    return *reinterpret_cast<short*>(&h);
}
__device__ inline float bf2f(short u) {
    union { unsigned int i; float f; } x;
    x.i = ((unsigned int)(unsigned short)u) << 16;
    return x.f;
}

// fragment-order index for element (k,n) of a 128x128 W, matching the
// MFMA B-fragment read: lane l reads slot (kb*8+nt)*64 + l as short8.
__device__ inline int fragidx(int k, int n) {
    int kb = k >> 5, kq = (k >> 3) & 3, j = k & 7;
    int nt = n >> 4, nl = n & 15;
    return (((kb * 8 + nt) * 64 + kq * 16 + nl) * 8 + j);
}

// ---------------------------------------------------------------------------
// Dispatch 1: blocks [0,64) = weight prep (frag bf16 Wt, W1, Wt@W0, bt@W0);
//             blocks [64, 64+NB) = zero counts.
// ---------------------------------------------------------------------------
__global__ __launch_bounds__(256) void prep_zero(const float* __restrict__ Wt,
                                                 const float* __restrict__ W0,
                                                 const float* __restrict__ W1,
                                                 const float* __restrict__ bt,
                                                 short* __restrict__ WtF,
                                                 short* __restrict__ WfF,
                                                 short* __restrict__ W1F,
                                                 float* __restrict__ btf,
                                                 int* __restrict__ counts) {
    int b = blockIdx.x;
    if (b < 64) {
        int gid = b * 256 + threadIdx.x;            // 0..16383
        int k = gid >> 7, n = gid & 127;
        float wf = 0.f;
        for (int kk = 0; kk < 128; ++kk)
            wf += Wt[k * 128 + kk] * W0[kk * 128 + n];
        int fi = fragidx(k, n);
        WtF[fi] = f2bf(Wt[k * 128 + n]);
        W1F[fi] = f2bf(W1[k * 128 + n]);
        WfF[fi] = f2bf(wf);
        if (gid < 128) {
            float s = 0.f;
            for (int kk = 0; kk < 128; ++kk) s += bt[kk] * W0[kk * 128 + n];
            btf[n] = s;
        }
    } else {
        int i = (b - 64) * 256 + threadIdx.x;
        if (i < N_NODES) counts[i] = 0;
    }
}

// ---------------------------------------------------------------------------
// Dispatch 2: blocks [0,GEMMB) = dual GEMM over x:
//   Hb = bf16(x@Wt + bt), Z = bf16(x@(Wt@W0) + bt@W0)
// blocks [GEMMB, GEMMB+HEB) = edge histogram (independent; fills CU bubbles).
// ---------------------------------------------------------------------------
__global__ __launch_bounds__(256) void dualgemm_hist(const float* __restrict__ A,
                                                     const short* __restrict__ WtF,
                                                     const short* __restrict__ WfF,
                                                     const float* __restrict__ bt,
                                                     const float* __restrict__ btf,
                                                     __hip_bfloat16* __restrict__ Hb,
                                                     __hip_bfloat16* __restrict__ Z,
                                                     const int* __restrict__ rows,
                                                     int* __restrict__ counts) {
    if (blockIdx.x >= GEMMB) {
        int gid = (blockIdx.x - GEMMB) * 256 + threadIdx.x;   // 0..319999
        atomicAdd(&counts[rows[gid]], 1);
        atomicAdd(&counts[rows[gid + HEB * 256]], 1);
        return;
    }

    const int t    = threadIdx.x;
    const int wave = t >> 6;
    const int l    = t & 63;
    const int nl   = l & 15;
    const int quad = l >> 4;
    const int wRow = blockIdx.x * 64 + wave * 16;

    f32x4 accH[8], accZ[8];
#pragma unroll
    for (int nt = 0; nt < 8; ++nt) {
        accH[nt] = (f32x4){0.f, 0.f, 0.f, 0.f};
        accZ[nt] = (f32x4){0.f, 0.f, 0.f, 0.f};
    }

#pragma unroll
    for (int kb = 0; kb < 4; ++kb) {
        const float* ap = A + (size_t)(wRow + nl) * 128 + kb * 32 + quad * 8;
        float4 f0 = *(const float4*)ap;
        float4 f1 = *(const float4*)(ap + 4);
        short8 afrag;
        afrag[0] = f2bf(f0.x); afrag[1] = f2bf(f0.y);
        afrag[2] = f2bf(f0.z); afrag[3] = f2bf(f0.w);
        afrag[4] = f2bf(f1.x); afrag[5] = f2bf(f1.y);
        afrag[6] = f2bf(f1.z); afrag[7] = f2bf(f1.w);
#pragma unroll
        for (int nt = 0; nt < 8; ++nt) {
            int off = ((kb * 8 + nt) * 64 + l) * 8;
            short8 bt_frag = *(const short8*)&WtF[off];
            short8 bf_frag = *(const short8*)&WfF[off];
            accH[nt] = __builtin_amdgcn_mfma_f32_16x16x32_bf16(afrag, bt_frag, accH[nt], 0, 0, 0);
            accZ[nt] = __builtin_amdgcn_mfma_f32_16x16x32_bf16(afrag, bf_frag, accZ[nt], 0, 0, 0);
        }
    }

#pragma unroll
    for (int nt = 0; nt < 8; ++nt) {
        int col = nt * 16 + nl;
        float bH = bt[col];
        float bZ = btf[col];
#pragma unroll
        for (int r = 0; r < 4; ++r) {
            int row = wRow + quad * 4 + r;
            *(short*)&Hb[(size_t)row * 128 + col] = f2bf(accH[nt][r] + bH);
            *(short*)&Z[(size_t)row * 128 + col]  = f2bf(accZ[nt][r] + bZ);
        }
    }
}

// ---------------------------------------------------------------------------
// scan pass 1: per-block exclusive scan of counts + block totals
// ---------------------------------------------------------------------------
__global__ __launch_bounds__(256) void scan_local(const int* __restrict__ counts,
                                                  int* __restrict__ excl,
                                                  int* __restrict__ blkTot) {
    __shared__ int sh[256];
    const int t = threadIdx.x;
    int i = blockIdx.x * 256 + t;
    int c = (i < N_NODES) ? counts[i] : 0;
    int val = c;
    sh[t] = val;
    __syncthreads();
    for (int off = 1; off < 256; off <<= 1) {
        int a = (t >= off) ? sh[t - off] : 0;
        __syncthreads();
        val += a;
        sh[t] = val;
        __syncthreads();
    }
    if (i < N_NODES) excl[i] = val - c;
    if (t == 255) blkTot[blockIdx.x] = val;
}

// ---------------------------------------------------------------------------
// scan pass 2: every block redundantly scans the NB block totals in LDS,
// picks its own offset, finalizes cursor/row_ptr.
// ---------------------------------------------------------------------------
__global__ __launch_bounds__(256) void scan_final(const int* __restrict__ excl,
                                                  const int* __restrict__ blkTot,
                                                  int* __restrict__ cursor,
                                                  int* __restrict__ row_ptr) {
    __shared__ int sh[256];
    const int t = threadIdx.x;
    int v = (t < NB) ? blkTot[t] : 0;
    int val = v;
    sh[t] = val;
    __syncthreads();
    for (int off = 1; off < 256; off <<= 1) {
        int a = (t >= off) ? sh[t - off] : 0;
        __syncthreads();
        val += a;
        sh[t] = val;
        __syncthreads();
    }
    int blkOff = (blockIdx.x == 0) ? 0 : sh[blockIdx.x - 1];
    int i = blockIdx.x * 256 + t;
    if (i < N_NODES) {
        int u = excl[i] + blkOff;
        cursor[i]  = u;
        row_ptr[i] = u;
    }
    if (i == 0) row_ptr[N_NODES] = N_EDGES;
}

// ---------------------------------------------------------------------------
// scatter: adj (u16 node ids) bucketed by destination via atomic cursor
// ---------------------------------------------------------------------------
__global__ __launch_bounds__(256) void scatter_kernel(const int* __restrict__ rows,
                                                      const int* __restrict__ cols,
                                                      int* __restrict__ cursor,
                                                      unsigned short* __restrict__ adj) {
    int gid = blockIdx.x * 256 + threadIdx.x;     // 0..319999
#pragma unroll
    for (int h = 0; h < 2; ++h) {
        int e   = gid + h * HEB * 256;
        int r   = rows[e];
        int pos = atomicAdd(&cursor[r], 1);
        adj[pos] = (unsigned short)cols[e];
    }
}

// ---------------------------------------------------------------------------
// Aggregation: one wave per node, 4 edges/group, up to 4 groups in flight.
// FINAL=0: Hb[node] = bf16(Hb[node] + relu(agg + bias))
// FINAL=1: Hout[node] = f32(Hb[node]) + relu(agg + bias)
// ---------------------------------------------------------------------------
template <int FINAL>
__global__ __launch_bounds__(256) void agg_kernel(const __hip_bfloat16* __restrict__ z,
                                                  const int* __restrict__ row_ptr,
                                                  const unsigned short* __restrict__ adj,
                                                  const float* __restrict__ bias,
                                                  __hip_bfloat16* __restrict__ Hb,
                                                  float* __restrict__ Hout) {
    const int wave = threadIdx.x >> 6;
    const int l    = threadIdx.x & 63;
    const int quad = l >> 4;
    const int sl   = l & 15;
    const int node = blockIdx.x * 4 + wave;
    if (node >= N_NODES) return;

    const int s = row_ptr[node];
    const int e = row_ptr[node + 1];

    float acc[8];
#pragma unroll
    for (int j = 0; j < 8; ++j) acc[j] = 0.f;

    int it = s + quad;
    for (; it + 12 < e; it += 16) {
        int c0 = adj[it];
        int c1 = adj[it + 4];
        int c2 = adj[it + 8];
        int c3 = adj[it + 12];
        short8 v0 = *(const short8*)&z[(size_t)c0 * DIM + sl * 8];
        short8 v1 = *(const short8*)&z[(size_t)c1 * DIM + sl * 8];
        short8 v2 = *(const short8*)&z[(size_t)c2 * DIM + sl * 8];
        short8 v3 = *(const short8*)&z[(size_t)c3 * DIM + sl * 8];
#pragma unroll
        for (int j = 0; j < 8; ++j)
            acc[j] += (bf2f(v0[j]) + bf2f(v1[j])) + (bf2f(v2[j]) + bf2f(v3[j]));
    }
    for (; it + 4 < e; it += 8) {
        int c0 = adj[it];
        int c1 = adj[it + 4];
        short8 v0 = *(const short8*)&z[(size_t)c0 * DIM + sl * 8];
        short8 v1 = *(const short8*)&z[(size_t)c1 * DIM + sl * 8];
#pragma unroll
        for (int j = 0; j < 8; ++j) acc[j] += bf2f(v0[j]) + bf2f(v1[j]);
    }
    if (it < e) {
        int c = adj[it];
        short8 v = *(const short8*)&z[(size_t)c * DIM + sl * 8];
#pragma unroll
        for (int j = 0; j < 8; ++j) acc[j] += bf2f(v[j]);
    }

#pragma unroll
    for (int j = 0; j < 8; ++j) acc[j] += __shfl_xor(acc[j], 16, 64);
#pragma unroll
    for (int j = 0; j < 8; ++j) acc[j] += __shfl_xor(acc[j], 32, 64);

    if (quad == 0) {
        short8 hrow = *(const short8*)((const short*)Hb + (size_t)node * DIM + sl * 8);
        float4 b0 = *(const float4*)&bias[sl * 8];
        float4 b1 = *(const float4*)&bias[sl * 8 + 4];
        float r[8];
        r[0] = acc[0] + b0.x; r[1] = acc[1] + b0.y; r[2] = acc[2] + b0.z; r[3] = acc[3] + b0.w;
        r[4] = acc[4] + b1.x; r[5] = acc[5] + b1.y; r[6] = acc[6] + b1.z; r[7] = acc[7] + b1.w;
#pragma unroll
        for (int j = 0; j < 8; ++j) {
            float rr = r[j] > 0.f ? r[j] : 0.f;
            r[j] = bf2f(hrow[j]) + rr;
        }
        if (FINAL) {
            float* hp = Hout + (size_t)node * DIM + sl * 8;
            *(float4*)hp       = make_float4(r[0], r[1], r[2], r[3]);
            *(float4*)(hp + 4) = make_float4(r[4], r[5], r[6], r[7]);
        } else {
            short8 o;
#pragma unroll
            for (int j = 0; j < 8; ++j) o[j] = f2bf(r[j]);
            *(short8*)((short*)Hb + (size_t)node * DIM + sl * 8) = o;
        }
    }
}

// ---------------------------------------------------------------------------
// bf16-A GEMM: Z = Hb@W1F (bf16 out, no bias)
// ---------------------------------------------------------------------------
__global__ __launch_bounds__(256) void gemm_bf16(const __hip_bfloat16* __restrict__ Hb,
                                                 const short* __restrict__ WF,
                                                 __hip_bfloat16* __restrict__ Z) {
    const int t    = threadIdx.x;
    const int wave = t >> 6;
    const int l    = t & 63;
    const int nl   = l & 15;
    const int quad = l >> 4;
    const int wRow = blockIdx.x * 64 + wave * 16;

    f32x4 acc[8];
#pragma unroll
    for (int nt = 0; nt < 8; ++nt) acc[nt] = (f32x4){0.f, 0.f, 0.f, 0.f};

#pragma unroll
    for (int kb = 0; kb < 4; ++kb) {
        short8 afrag = *(const short8*)((const short*)Hb + (size_t)(wRow + nl) * 128 + kb * 32 + quad * 8);
#pragma unroll
        for (int nt = 0; nt < 8; ++nt) {
            short8 bfrag = *(const short8*)&WF[((kb * 8 + nt) * 64 + l) * 8];
            acc[nt] = __builtin_amdgcn_mfma_f32_16x16x32_bf16(afrag, bfrag, acc[nt], 0, 0, 0);
        }
    }

#pragma unroll
    for (int nt = 0; nt < 8; ++nt) {
        int col = nt * 16 + nl;
#pragma unroll
        for (int r = 0; r < 4; ++r) {
            int row = wRow + quad * 4 + r;
            *(short*)&Z[(size_t)row * 128 + col] = f2bf(acc[nt][r]);
        }
    }
}

// ---------------------------------------------------------------------------
extern "C" void kernel_launch(void* const* d_in, const int* in_sizes, int n_in,
                              void* d_out, int out_size, void* d_ws, size_t ws_size,
                              hipStream_t stream) {
    const float* x   = (const float*)d_in[0];
    const int*   ei  = (const int*)d_in[1];
    const float* W_t = (const float*)d_in[2];
    const float* b_t = (const float*)d_in[3];
    const float* W0  = (const float*)d_in[4];
    const float* b0  = (const float*)d_in[5];
    const float* W1  = (const float*)d_in[6];
    const float* b1  = (const float*)d_in[7];

    const int* rows = ei;
    const int* cols = ei + N_EDGES;

    float* H = (float*)d_out;

    // workspace layout (~22.6 MB)
    char* w = (char*)d_ws;
    __hip_bfloat16* Z  = (__hip_bfloat16*)w;  w += (size_t)N_NODES * DIM * 2;
    __hip_bfloat16* Hb = (__hip_bfloat16*)w;  w += (size_t)N_NODES * DIM * 2;
    short* WtF = (short*)w;  w += 128 * 128 * 2;
    short* WfF = (short*)w;  w += 128 * 128 * 2;
    short* W1F = (short*)w;  w += 128 * 128 * 2;
    float* btf = (float*)w;  w += 128 * 4;
    int* row_ptr = (int*)w;  w += (N_NODES + 1) * 4;
    int* cursor  = (int*)w;  w += N_NODES * 4;
    int* counts  = (int*)w;  w += N_NODES * 4;
    int* excl    = (int*)w;  w += N_NODES * 4;
    int* blkTot  = (int*)w;  w += 256 * 4;
    unsigned short* adj = (unsigned short*)w;   // E u16

    const int aggBlocks = (N_NODES + 3) / 4;

    // 1: weight prep | zero counts
    prep_zero<<<64 + NB, 256, 0, stream>>>(W_t, W0, W1, b_t, WtF, WfF, W1F, btf, counts);

    // 2: dual GEMM over x | edge histogram (independent, overlapped)
    dualgemm_hist<<<GEMMB + HEB, 256, 0, stream>>>(x, WtF, WfF, b_t, btf, Hb, Z,
                                                   rows, counts);

    // 3-4: two-level scan -> row_ptr / cursor
    scan_local<<<NB, 256, 0, stream>>>(counts, excl, blkTot);
    scan_final<<<NB, 256, 0, stream>>>(excl, blkTot, cursor, row_ptr);

    // 5: bucket edges by destination (u16 adj)
    scatter_kernel<<<HEB, 256, 0, stream>>>(rows, cols, cursor, adj);

    // 6: layer 0 agg: Hb += relu(agg(Z0) + b0)   (bf16 in-place)
    agg_kernel<0><<<aggBlocks, 256, 0, stream>>>(Z, row_ptr, adj, b0, Hb, nullptr);

    // 7: Z1 = Hb@W1
    gemm_bf16<<<GEMMB, 256, 0, stream>>>(Hb, W1F, Z);

    // 8: layer 1 agg: H = f32(Hb) + relu(agg(Z1) + b1)
    agg_kernel<1><<<aggBlocks, 256, 0, stream>>>(Z, row_ptr, adj, b1, Hb, H);
}